// Round 9
// baseline (192.886 us; speedup 1.0000x reference)
//
#include <hip/hip_runtime.h>
#include <math.h>

#define DD 768
#define DD4 192          // DD/4
#define KK 16
#define KCACHE 4         // centroids 0..3 live in registers (12 float4/lane)
#define EPSV 1e-5f
#define SCRS 40          // 38 value slots (d1 @20 for 16B align) + pad
#define NWAVES 8         // 512-thread blocks: 8 waves share the 48 KB centroid tile

// R7 post-mortem: the per-CU LDS pipe is ~68% busy (48 b128 centroid reads +
// 52 scratch b32 ops ~= 900 DS-cycles/iter x 128 iters/CU ~= 48us of 70us).
// This round cuts DS work ~26%:
//  - centroids k=0..3 cached in registers (48 -> 36 b128 reads/iter)
//  - scratch writes packed b128/b64 (36 -> 10 DS ops/iter)
// Structure frozen at R7: 512thd, grid 1024, stride-8192, (512,2) loose cap
// (R7 showed the compiler picks the natural VGPR count; hard caps spill —
// R6: cap 128 w/ ~170-reg body -> 2.3x HBM traffic).
// Do not re-add: nt stores (R3/R5), strided persistent sweep (R5/R6).
__global__ __launch_bounds__(512, 2)
void sln_kernel(const float* __restrict__ x,
                const float* __restrict__ weights,
                const float* __restrict__ biases,
                const float* __restrict__ centroids,
                float* __restrict__ out,       // [nrows*DD]
                float* __restrict__ bkt,       // [nrows] bucket idx as float
                int nrows)
{
    __shared__ float cs[KK * DD];              // 48 KB
    __shared__ float c2s[KK];
    __shared__ float scr[NWAVES][16][SCRS];    // per-wave transpose scratch (20.5 KB)

    const int tid  = threadIdx.x;
    const int lane = tid & 63;
    const int wave = tid >> 6;

    // stage centroids to LDS (coalesced float4)
    {
        const float4* c4 = (const float4*)centroids;
        float4* cs4w = (float4*)cs;
        for (int i = tid; i < KK * DD4; i += 512) cs4w[i] = c4[i];
    }
    __syncthreads();

    // c2[k] = sum_d centroids[k][d]^2  (reuse scr as 512-float scratch)
    {
        float* part = &scr[0][0][0];
        int k = tid >> 5, t = tid & 31;
        float p = 0.f;
        #pragma unroll
        for (int j = 0; j < DD / 32; ++j) {
            float v = cs[k * DD + t + 32 * j];
            p += v * v;
        }
        part[tid] = p;
    }
    __syncthreads();
    if (tid < KK) {
        float* part = &scr[0][0][0];
        float sacc = 0.f;
        #pragma unroll
        for (int i = 0; i < 32; ++i) sacc += part[tid * 32 + i];
        c2s[tid] = sacc;
    }
    __syncthreads();

    const float4* cs4 = (const float4*)cs;

    // register-cache centroids k=0..KCACHE-1 for this lane's 12 elements.
    // Unrolled -> compile-time indices -> stays in VGPRs (48 regs).
    float4 cc[KCACHE][3];
    #pragma unroll
    for (int k = 0; k < KCACHE; ++k) {
        cc[k][0] = cs4[k * DD4 + lane];
        cc[k][1] = cs4[k * DD4 + lane + 64];
        cc[k][2] = cs4[k * DD4 + lane + 128];
    }

    const int gw = blockIdx.x * NWAVES + wave;
    const int wstride = gridDim.x * NWAVES;    // 8192

    for (int pair = gw; pair * 2 < nrows; pair += wstride) {
        const int r0 = pair * 2;
        const int r1 = r0 + 1;

        const float4* xr0 = (const float4*)(x + (size_t)r0 * DD);
        const float4* xr1 = (const float4*)(x + (size_t)r1 * DD);
        float4 a0 = xr0[lane], a1 = xr0[lane + 64], a2 = xr0[lane + 128];
        float4 b0 = xr1[lane], b1 = xr1[lane + 64], b2 = xr1[lane + 128];

        // per-lane partials
        float s0 = a0.x+a0.y+a0.z+a0.w + a1.x+a1.y+a1.z+a1.w + a2.x+a2.y+a2.z+a2.w;
        float ss0 = a0.x*a0.x+a0.y*a0.y+a0.z*a0.z+a0.w*a0.w
                  + a1.x*a1.x+a1.y*a1.y+a1.z*a1.z+a1.w*a1.w
                  + a2.x*a2.x+a2.y*a2.y+a2.z*a2.z+a2.w*a2.w;
        float s1 = b0.x+b0.y+b0.z+b0.w + b1.x+b1.y+b1.z+b1.w + b2.x+b2.y+b2.z+b2.w;
        float ss1 = b0.x*b0.x+b0.y*b0.y+b0.z*b0.z+b0.w*b0.w
                  + b1.x*b1.x+b1.y*b1.y+b1.z*b1.z+b1.w*b1.w
                  + b2.x*b2.x+b2.y*b2.y+b2.z*b2.z+b2.w*b2.w;

        float d0[KK], d1[KK];
        // cached centroids: zero LDS traffic
        #pragma unroll
        for (int k = 0; k < KCACHE; ++k) {
            float4 c0 = cc[k][0], c1 = cc[k][1], c2 = cc[k][2];
            d0[k] = a0.x*c0.x + a0.y*c0.y + a0.z*c0.z + a0.w*c0.w
                  + a1.x*c1.x + a1.y*c1.y + a1.z*c1.z + a1.w*c1.w
                  + a2.x*c2.x + a2.y*c2.y + a2.z*c2.z + a2.w*c2.w;
            d1[k] = b0.x*c0.x + b0.y*c0.y + b0.z*c0.z + b0.w*c0.w
                  + b1.x*c1.x + b1.y*c1.y + b1.z*c1.z + b1.w*c1.w
                  + b2.x*c2.x + b2.y*c2.y + b2.z*c2.z + b2.w*c2.w;
        }
        // remaining centroids from LDS
        #pragma unroll
        for (int k = KCACHE; k < KK; ++k) {
            float4 c0 = cs4[k * DD4 + lane];
            float4 c1 = cs4[k * DD4 + lane + 64];
            float4 c2 = cs4[k * DD4 + lane + 128];
            d0[k] = a0.x*c0.x + a0.y*c0.y + a0.z*c0.z + a0.w*c0.w
                  + a1.x*c1.x + a1.y*c1.y + a1.z*c1.z + a1.w*c1.w
                  + a2.x*c2.x + a2.y*c2.y + a2.z*c2.z + a2.w*c2.w;
            d1[k] = b0.x*c0.x + b0.y*c0.y + b0.z*c0.z + b0.w*c0.w
                  + b1.x*c1.x + b1.y*c1.y + b1.z*c1.z + b1.w*c1.w
                  + b2.x*c2.x + b2.y*c2.y + b2.z*c2.z + b2.w*c2.w;
        }

        // 2-step quad reduce (independent shuffles, short chains)
        #pragma unroll
        for (int k = 0; k < KK; ++k) {
            d0[k] += __shfl_xor(d0[k], 1); d0[k] += __shfl_xor(d0[k], 2);
            d1[k] += __shfl_xor(d1[k], 1); d1[k] += __shfl_xor(d1[k], 2);
        }
        s0 += __shfl_xor(s0, 1);  s0 += __shfl_xor(s0, 2);
        ss0 += __shfl_xor(ss0, 1); ss0 += __shfl_xor(ss0, 2);
        s1 += __shfl_xor(s1, 1);  s1 += __shfl_xor(s1, 2);
        ss1 += __shfl_xor(ss1, 1); ss1 += __shfl_xor(ss1, 2);

        // quad leaders write 38 values, PACKED: row0 d @0..15, s/ss @16..17;
        // row1 d @20..35 (16B aligned), s/ss @36..37.
        if ((lane & 3) == 0) {
            int q = lane >> 2;
            float* p = &scr[wave][q][0];
            float4* p4 = (float4*)p;
            p4[0] = make_float4(d0[0],  d0[1],  d0[2],  d0[3]);
            p4[1] = make_float4(d0[4],  d0[5],  d0[6],  d0[7]);
            p4[2] = make_float4(d0[8],  d0[9],  d0[10], d0[11]);
            p4[3] = make_float4(d0[12], d0[13], d0[14], d0[15]);
            *(float2*)(p + 16) = make_float2(s0, ss0);
            float4* q4 = (float4*)(p + 20);
            q4[0] = make_float4(d1[0],  d1[1],  d1[2],  d1[3]);
            q4[1] = make_float4(d1[4],  d1[5],  d1[6],  d1[7]);
            q4[2] = make_float4(d1[8],  d1[9],  d1[10], d1[11]);
            q4[3] = make_float4(d1[12], d1[13], d1[14], d1[15]);
            *(float2*)(p + 36) = make_float2(s1, ss1);
        }
        __asm__ volatile("" ::: "memory");   // intra-wave LDS RAW: in-order per wave

        // transpose read: lanes 0..17 -> row0 slots 0..17,
        //                 lanes 32..49 -> row1 slots 20..37
        int slot = (lane < 32) ? lane : (20 + (lane - 32));
        float T = 0.f;
        if (lane < 18 || (lane >= 32 && lane < 50)) {
            float t0 = 0.f, t1 = 0.f, t2 = 0.f, t3 = 0.f;
            #pragma unroll
            for (int q = 0; q < 16; q += 4) {
                t0 += scr[wave][q + 0][slot];
                t1 += scr[wave][q + 1][slot];
                t2 += scr[wave][q + 2][slot];
                t3 += scr[wave][q + 3][slot];
            }
            T = (t0 + t1) + (t2 + t3);
        }
        __asm__ volatile("" ::: "memory");

        // broadcast row sums (slot16/17 -> lane16/17; slot36/37 -> lane48/49)
        float sA  = __shfl(T, 16), ssA = __shfl(T, 17);
        float sB  = __shfl(T, 48), ssB = __shfl(T, 49);

        // argmin over 16 dists (lanes 0..15 = row0, 32..47 = row1)
        int v = lane & 15;
        float ssSel = (lane & 32) ? ssB : ssA;
        float sq = (ssSel - 2.f * T) + c2s[v];
        int idx = v;
        #pragma unroll
        for (int m = 1; m < 16; m <<= 1) {
            float osq = __shfl_xor(sq, m);
            int   oidx = __shfl_xor(idx, m);
            bool take = (osq < sq) || (osq == sq && oidx < idx);
            sq  = take ? osq  : sq;
            idx = take ? oidx : idx;
        }
        int bk0 = __builtin_amdgcn_readlane(idx, 0);
        int bk1 = __builtin_amdgcn_readlane(idx, 32);

        float mean0 = sA * (1.f / DD);
        float mean1 = sB * (1.f / DD);
        float rstd0 = 1.f / sqrtf(ssA * (1.f / DD) - mean0 * mean0 + EPSV);
        float rstd1 = 1.f / sqrtf(ssB * (1.f / DD) - mean1 * mean1 + EPSV);

        if (lane == 0) {
            bkt[r0] = (float)bk0;
            bkt[r1] = (float)bk1;
        }

        const float4* w0 = (const float4*)(weights + (size_t)bk0 * DD);
        const float4* g0 = (const float4*)(biases  + (size_t)bk0 * DD);
        const float4* w1 = (const float4*)(weights + (size_t)bk1 * DD);
        const float4* g1 = (const float4*)(biases  + (size_t)bk1 * DD);
        float4* o0 = (float4*)(out + (size_t)r0 * DD);
        float4* o1 = (float4*)(out + (size_t)r1 * DD);

        #pragma unroll
        for (int j = 0; j < 3; ++j) {
            float4 xv = (j == 0) ? a0 : (j == 1) ? a1 : a2;
            float4 wv = w0[lane + 64 * j];
            float4 bv = g0[lane + 64 * j];
            float4 o;
            o.x = (xv.x - mean0) * rstd0 * wv.x + bv.x;
            o.y = (xv.y - mean0) * rstd0 * wv.y + bv.y;
            o.z = (xv.z - mean0) * rstd0 * wv.z + bv.z;
            o.w = (xv.w - mean0) * rstd0 * wv.w + bv.w;
            o0[lane + 64 * j] = o;
        }
        #pragma unroll
        for (int j = 0; j < 3; ++j) {
            float4 xv = (j == 0) ? b0 : (j == 1) ? b1 : b2;
            float4 wv = w1[lane + 64 * j];
            float4 bv = g1[lane + 64 * j];
            float4 o;
            o.x = (xv.x - mean1) * rstd1 * wv.x + bv.x;
            o.y = (xv.y - mean1) * rstd1 * wv.y + bv.y;
            o.z = (xv.z - mean1) * rstd1 * wv.z + bv.z;
            o.w = (xv.w - mean1) * rstd1 * wv.w + bv.w;
            o1[lane + 64 * j] = o;
        }
    }
}

extern "C" void kernel_launch(void* const* d_in, const int* in_sizes, int n_in,
                              void* d_out, int out_size, void* d_ws, size_t ws_size,
                              hipStream_t stream) {
    const float* x         = (const float*)d_in[0];
    const float* weights   = (const float*)d_in[1];
    const float* biases    = (const float*)d_in[2];
    const float* centroids = (const float*)d_in[3];

    const int nrows = in_sizes[0] / DD;   // B*S = 32768

    float* out = (float*)d_out;
    float* bkt = out + (size_t)nrows * DD;

    // 1024 blocks x 8 waves = 8192 wave-streams; 16384 pairs -> 2 per wave,
    // stride 8192 (the R1/R7 geometry).
    dim3 grid(1024), block(512);
    hipLaunchKernelGGL(sln_kernel, grid, block, 0, stream,
                       x, weights, biases, centroids, out, bkt, nrows);
}

// Round 10
// 188.734 us; speedup vs baseline: 1.0220x; 1.0220x over previous
//
#include <hip/hip_runtime.h>
#include <math.h>

#define DD 768
#define DD4 192          // DD/4
#define KK 16
#define EPSV 1e-5f
#define SCRS 38          // 36 value slots + 2 pad -> stride 38: 6q%32 = 16 distinct banks
#define NWAVES 8         // 512-thread blocks: 8 waves share the 48 KB centroid tile

// R9 post-mortem: packed b128 scratch writes at SCRS=40 (stride 160B) made
// quad-leader writes collide 4-way -> SQ_LDS_BANK_CONFLICT 49K->836K,
// dur 70->87us. KCACHE was a no-op (VGPR 88 != ~136 needed; compiler
// rematerialized). Both reverted; base = R7 (69.5-71.7us measured).
//
// This round (single change): quad-reduce via DPP quad_perm instead of
// __shfl_xor. __shfl_xor = ds_swizzle = DS-pipe op; the 72 reduce shuffles
// were ~430 of ~1280 DS-cycles/iter on the per-CU-shared LDS unit (~34us
// of 70us). DPP xor1 (0xB1) / xor2 (0x4E) are VALU adds: zero DS traffic,
// ~4cyc dependent latency vs a swizzle round-trip.
//
// Frozen structure: 512thd, grid 1024, stride-8192, (512,2) loose VGPR cap.
// Do not re-add: nt stores (R3/R5), strided persistent sweep (R5/R6),
// register prefetch under a tight cap (R6), packed scratch writes (R9).
__device__ __forceinline__ float dpp_xor1_add(float v) {
    int s = __builtin_amdgcn_update_dpp(0, __float_as_int(v), 0xB1, 0xF, 0xF, true);
    return v + __int_as_float(s);
}
__device__ __forceinline__ float dpp_xor2_add(float v) {
    int s = __builtin_amdgcn_update_dpp(0, __float_as_int(v), 0x4E, 0xF, 0xF, true);
    return v + __int_as_float(s);
}

__global__ __launch_bounds__(512, 2)
void sln_kernel(const float* __restrict__ x,
                const float* __restrict__ weights,
                const float* __restrict__ biases,
                const float* __restrict__ centroids,
                float* __restrict__ out,       // [nrows*DD]
                float* __restrict__ bkt,       // [nrows] bucket idx as float
                int nrows)
{
    __shared__ float cs[KK * DD];              // 48 KB
    __shared__ float c2s[KK];
    __shared__ float scr[NWAVES][16][SCRS];    // per-wave transpose scratch

    const int tid  = threadIdx.x;
    const int lane = tid & 63;
    const int wave = tid >> 6;

    // stage centroids to LDS (coalesced float4)
    {
        const float4* c4 = (const float4*)centroids;
        float4* cs4w = (float4*)cs;
        for (int i = tid; i < KK * DD4; i += 512) cs4w[i] = c4[i];
    }
    __syncthreads();

    // c2[k] = sum_d centroids[k][d]^2  (reuse scr as 512-float scratch)
    {
        float* part = &scr[0][0][0];
        int k = tid >> 5, t = tid & 31;
        float p = 0.f;
        #pragma unroll
        for (int j = 0; j < DD / 32; ++j) {
            float v = cs[k * DD + t + 32 * j];
            p += v * v;
        }
        part[tid] = p;
    }
    __syncthreads();
    if (tid < KK) {
        float* part = &scr[0][0][0];
        float sacc = 0.f;
        #pragma unroll
        for (int i = 0; i < 32; ++i) sacc += part[tid * 32 + i];
        c2s[tid] = sacc;
    }
    __syncthreads();

    const float4* cs4 = (const float4*)cs;
    const int gw = blockIdx.x * NWAVES + wave;
    const int wstride = gridDim.x * NWAVES;    // 8192

    for (int pair = gw; pair * 2 < nrows; pair += wstride) {
        const int r0 = pair * 2;
        const int r1 = r0 + 1;

        const float4* xr0 = (const float4*)(x + (size_t)r0 * DD);
        const float4* xr1 = (const float4*)(x + (size_t)r1 * DD);
        float4 a0 = xr0[lane], a1 = xr0[lane + 64], a2 = xr0[lane + 128];
        float4 b0 = xr1[lane], b1 = xr1[lane + 64], b2 = xr1[lane + 128];

        // per-lane partials
        float s0 = a0.x+a0.y+a0.z+a0.w + a1.x+a1.y+a1.z+a1.w + a2.x+a2.y+a2.z+a2.w;
        float ss0 = a0.x*a0.x+a0.y*a0.y+a0.z*a0.z+a0.w*a0.w
                  + a1.x*a1.x+a1.y*a1.y+a1.z*a1.z+a1.w*a1.w
                  + a2.x*a2.x+a2.y*a2.y+a2.z*a2.z+a2.w*a2.w;
        float s1 = b0.x+b0.y+b0.z+b0.w + b1.x+b1.y+b1.z+b1.w + b2.x+b2.y+b2.z+b2.w;
        float ss1 = b0.x*b0.x+b0.y*b0.y+b0.z*b0.z+b0.w*b0.w
                  + b1.x*b1.x+b1.y*b1.y+b1.z*b1.z+b1.w*b1.w
                  + b2.x*b2.x+b2.y*b2.y+b2.z*b2.z+b2.w*b2.w;

        float d0[KK], d1[KK];
        #pragma unroll
        for (int k = 0; k < KK; ++k) {
            float4 c0 = cs4[k * DD4 + lane];
            float4 c1 = cs4[k * DD4 + lane + 64];
            float4 c2 = cs4[k * DD4 + lane + 128];
            d0[k] = a0.x*c0.x + a0.y*c0.y + a0.z*c0.z + a0.w*c0.w
                  + a1.x*c1.x + a1.y*c1.y + a1.z*c1.z + a1.w*c1.w
                  + a2.x*c2.x + a2.y*c2.y + a2.z*c2.z + a2.w*c2.w;
            d1[k] = b0.x*c0.x + b0.y*c0.y + b0.z*c0.z + b0.w*c0.w
                  + b1.x*c1.x + b1.y*c1.y + b1.z*c1.z + b1.w*c1.w
                  + b2.x*c2.x + b2.y*c2.y + b2.z*c2.z + b2.w*c2.w;
        }

        // 2-step quad reduce on the VALU (DPP quad_perm) — no DS traffic
        #pragma unroll
        for (int k = 0; k < KK; ++k) {
            d0[k] = dpp_xor2_add(dpp_xor1_add(d0[k]));
            d1[k] = dpp_xor2_add(dpp_xor1_add(d1[k]));
        }
        s0  = dpp_xor2_add(dpp_xor1_add(s0));
        ss0 = dpp_xor2_add(dpp_xor1_add(ss0));
        s1  = dpp_xor2_add(dpp_xor1_add(s1));
        ss1 = dpp_xor2_add(dpp_xor1_add(ss1));

        // quad leaders write 36 values (row0: 0..17, row1: 18..35)
        if ((lane & 3) == 0) {
            int q = lane >> 2;
            float* p = &scr[wave][q][0];
            #pragma unroll
            for (int k = 0; k < KK; ++k) { p[k] = d0[k]; p[18 + k] = d1[k]; }
            p[16] = s0; p[17] = ss0; p[34] = s1; p[35] = ss1;
        }
        __asm__ volatile("" ::: "memory");   // intra-wave LDS RAW: in-order per wave

        // transpose read: lanes 0..17 -> row0 values, lanes 32..49 -> row1 values
        int slot = (lane < 32) ? lane : (18 + (lane - 32));
        float T = 0.f;
        if (lane < 18 || (lane >= 32 && lane < 50)) {
            float t0 = 0.f, t1 = 0.f, t2 = 0.f, t3 = 0.f;
            #pragma unroll
            for (int q = 0; q < 16; q += 4) {
                t0 += scr[wave][q + 0][slot];
                t1 += scr[wave][q + 1][slot];
                t2 += scr[wave][q + 2][slot];
                t3 += scr[wave][q + 3][slot];
            }
            T = (t0 + t1) + (t2 + t3);
        }
        __asm__ volatile("" ::: "memory");

        // broadcast row sums
        float sA  = __shfl(T, 16), ssA = __shfl(T, 17);
        float sB  = __shfl(T, 48), ssB = __shfl(T, 49);

        // argmin over 16 dists (lanes 0..15 = row0, 32..47 = row1)
        int v = lane & 15;
        float ssSel = (lane & 32) ? ssB : ssA;
        float sq = (ssSel - 2.f * T) + c2s[v];
        int idx = v;
        #pragma unroll
        for (int m = 1; m < 16; m <<= 1) {
            float osq = __shfl_xor(sq, m);
            int   oidx = __shfl_xor(idx, m);
            bool take = (osq < sq) || (osq == sq && oidx < idx);
            sq  = take ? osq  : sq;
            idx = take ? oidx : idx;
        }
        int bk0 = __builtin_amdgcn_readlane(idx, 0);
        int bk1 = __builtin_amdgcn_readlane(idx, 32);

        float mean0 = sA * (1.f / DD);
        float mean1 = sB * (1.f / DD);
        float rstd0 = 1.f / sqrtf(ssA * (1.f / DD) - mean0 * mean0 + EPSV);
        float rstd1 = 1.f / sqrtf(ssB * (1.f / DD) - mean1 * mean1 + EPSV);

        if (lane == 0) {
            bkt[r0] = (float)bk0;
            bkt[r1] = (float)bk1;
        }

        const float4* w0 = (const float4*)(weights + (size_t)bk0 * DD);
        const float4* g0 = (const float4*)(biases  + (size_t)bk0 * DD);
        const float4* w1 = (const float4*)(weights + (size_t)bk1 * DD);
        const float4* g1 = (const float4*)(biases  + (size_t)bk1 * DD);
        float4* o0 = (float4*)(out + (size_t)r0 * DD);
        float4* o1 = (float4*)(out + (size_t)r1 * DD);

        #pragma unroll
        for (int j = 0; j < 3; ++j) {
            float4 xv = (j == 0) ? a0 : (j == 1) ? a1 : a2;
            float4 wv = w0[lane + 64 * j];
            float4 bv = g0[lane + 64 * j];
            float4 o;
            o.x = (xv.x - mean0) * rstd0 * wv.x + bv.x;
            o.y = (xv.y - mean0) * rstd0 * wv.y + bv.y;
            o.z = (xv.z - mean0) * rstd0 * wv.z + bv.z;
            o.w = (xv.w - mean0) * rstd0 * wv.w + bv.w;
            o0[lane + 64 * j] = o;
        }
        #pragma unroll
        for (int j = 0; j < 3; ++j) {
            float4 xv = (j == 0) ? b0 : (j == 1) ? b1 : b2;
            float4 wv = w1[lane + 64 * j];
            float4 bv = g1[lane + 64 * j];
            float4 o;
            o.x = (xv.x - mean1) * rstd1 * wv.x + bv.x;
            o.y = (xv.y - mean1) * rstd1 * wv.y + bv.y;
            o.z = (xv.z - mean1) * rstd1 * wv.z + bv.z;
            o.w = (xv.w - mean1) * rstd1 * wv.w + bv.w;
            o1[lane + 64 * j] = o;
        }
    }
}

extern "C" void kernel_launch(void* const* d_in, const int* in_sizes, int n_in,
                              void* d_out, int out_size, void* d_ws, size_t ws_size,
                              hipStream_t stream) {
    const float* x         = (const float*)d_in[0];
    const float* weights   = (const float*)d_in[1];
    const float* biases    = (const float*)d_in[2];
    const float* centroids = (const float*)d_in[3];

    const int nrows = in_sizes[0] / DD;   // B*S = 32768

    float* out = (float*)d_out;
    float* bkt = out + (size_t)nrows * DD;

    // 1024 blocks x 8 waves = 8192 wave-streams; 16384 pairs -> 2 per wave,
    // stride 8192 (the R1/R7 geometry).
    dim3 grid(1024), block(512);
    hipLaunchKernelGGL(sln_kernel, grid, block, 0, stream,
                       x, weights, biases, centroids, out, bkt, nrows);
}